// Round 8
// baseline (450.625 us; speedup 1.0000x reference)
//
#include <hip/hip_runtime.h>
#include <math.h>

#define HD    256
#define NHEAD 4
#define NSEG  1024
#define RPB   64                                    // rows per block
#define NRB64 6250                                  // 400000/64 row slabs

typedef short bf16x8 __attribute__((ext_vector_type(8)));
typedef float f32x16 __attribute__((ext_vector_type(16)));

__device__ __forceinline__ float tanh_fast(float v) {
    float e = __expf(2.0f * v);                    // overflow->inf, tanh->1: ok
    return 1.0f - 2.0f * __builtin_amdgcn_rcpf(e + 1.0f);
}

// split fp32 pair into packed bf16-hi word and bf16-lo word (truncation split;
// lo captures mantissa bits 9..17 -> per-product rel err ~2^-17)
__device__ __forceinline__ void split2(float a, float b, unsigned &hi, unsigned &lo) {
    unsigned ba = __float_as_uint(a), bb = __float_as_uint(b);
    unsigned ha = ba & 0xFFFF0000u, hb = bb & 0xFFFF0000u;
    float la = a - __uint_as_float(ha);
    float lb = b - __uint_as_float(hb);
    hi = (ha >> 16) | hb;
    lo = (__float_as_uint(la) >> 16) | (__float_as_uint(lb) & 0xFFFF0000u);
}

__device__ __forceinline__ void gld16(const void* g, void* l) {
    __builtin_amdgcn_global_load_lds(
        (const __attribute__((address_space(1))) void*)g,
        (__attribute__((address_space(3))) void*)l, 16, 0, 0);
}

// ---------------------------------------------------------------------------
// k0_prep: W1 (fp32 [k][c]) -> ws split-bf16 planes laid out exactly as k1's
// per-chunk LDS image: off = t*32768 + ch*16384 + pl*8192 + o*2048 + c*16 + j*4
// (t = KC=32 chunk, ch = col half, pl = hi/lo plane, o = k-oct, c = col in
//  half, j = k-pair). 256 KiB total.
// ---------------------------------------------------------------------------
__global__ __launch_bounds__(256) void k0_prep(
    const float* __restrict__ W1, char* __restrict__ ws)
{
    int g = blockIdx.x * 256 + threadIdx.x;        // 32768 threads
    int c  = g & 127;
    int j  = (g >> 7) & 3;
    int o  = (g >> 9) & 3;
    int ch = (g >> 11) & 1;
    int t  = g >> 12;
    int k   = t*32 + o*8 + 2*j;
    int col = ch*128 + c;
    float a = W1[(size_t)k * HD + col];
    float b = W1[(size_t)(k + 1) * HD + col];
    unsigned hw, lw;
    split2(a, b, hw, lw);
    size_t off = (size_t)t*32768 + ch*16384 + o*2048 + c*16 + j*4;
    *(unsigned*)(ws + off)        = hw;
    *(unsigned*)(ws + off + 8192) = lw;
}

// ---------------------------------------------------------------------------
// K1: partial logits for one 128-col half.
// 256 thr = 4 waves: rg = wid>>1 (2 x 32 rows), cg = wid&1 (2 x 64 cols).
// Wave tile 32x64 = 1rt x 2ct of 32x32 mfma -> acc = 32 AGPR.
// BOTH x and W staged via global_load_lds, KC=32 double-buffered:
// buffer = [W 16K | x 8K] x2 = 48 KB -> 3 blocks/CU (12 waves).
// Next chunk's loads issued BEFORE compute -> barrier drain overlaps compute
// of this block AND of the 2 other resident blocks (de-correlated drains).
// x staged fp32 with source-side slot^=(row&7) swizzle (R5-proven);
// split2 to bf16 hi/lo at consumption. Col-half blocks write partial logits
// lgA (+b2) / lgB; k2/k3 sum them. bid swizzle pairs ch-halves on one XCD.
// ---------------------------------------------------------------------------
#define K1_THREADS 256
#define BUFB 24576
#define K1_LDS (2*BUFB)

__global__ __launch_bounds__(K1_THREADS, 3) void k1_mfma(
    const float* __restrict__ x, const char* __restrict__ wsW,
    const float* __restrict__ b1, const float* __restrict__ W2,
    const float* __restrict__ b2, float* __restrict__ lgA,
    float* __restrict__ lgB, int N)
{
    extern __shared__ __align__(16) char smem[];

    const int raw = blockIdx.x;
    const int ch  = (raw >> 3) & 1;
    const int rb  = (raw >> 4) * 8 + (raw & 7);
    if (rb >= NRB64) return;

    const int tid  = threadIdx.x;
    const int lane = tid & 63;
    const int lo5  = lane & 31;
    const int hi   = lane >> 5;
    const int wid  = tid >> 6;
    const int rg   = wid >> 1;                     // 0..1 (32-row groups)
    const int cg   = wid & 1;                      // 0..1 (64-col groups)
    const int blkrow = rb * RPB;

    f32x16 acc[2];
    #pragma unroll
    for (int ct = 0; ct < 2; ++ct) {
        float b1v = b1[ch*128 + cg*64 + ct*32 + lo5];
        #pragma unroll
        for (int e = 0; e < 16; ++e) acc[ct][e] = b1v;
    }

    // x stage source (per thread, 2 pieces; advance by t*128 per chunk)
    const char* gx[2];
    #pragma unroll
    for (int i = 0; i < 2; ++i) {
        int p    = i*4096 + tid*16;                // offset in 8K x-region
        int row  = p >> 7;                         // 0..63
        int slot = (p >> 4) & 7;
        long grow = blkrow + row; if (grow > N-1) grow = N-1;
        gx[i] = (const char*)x + grow*1024 + ((slot ^ (row & 7)) * 16);
    }
    const char* gw = wsW + ch*16384 + tid*16;      // + t*32768 per chunk

    // prologue: stage chunk 0 -> buffer 0
    #pragma unroll
    for (int i = 0; i < 4; ++i) gld16(gw + i*4096, smem + i*4096 + tid*16);
    #pragma unroll
    for (int i = 0; i < 2; ++i) gld16(gx[i], smem + 16384 + i*4096 + tid*16);
    __syncthreads();

    for (int t = 0; t < 8; ++t) {
        const int buf  = (t & 1) * BUFB;
        const int nbuf = BUFB - buf;
        if (t < 7) {                               // issue next chunk first
            const char* srcw = gw + (size_t)(t+1)*32768;
            #pragma unroll
            for (int i = 0; i < 4; ++i)
                gld16(srcw + i*4096, smem + nbuf + i*4096 + tid*16);
            #pragma unroll
            for (int i = 0; i < 2; ++i)
                gld16(gx[i] + (size_t)(t+1)*128, smem + nbuf + 16384 + i*4096 + tid*16);
        }
        #pragma unroll
        for (int ks = 0; ks < 2; ++ks) {
            union { unsigned u[4]; bf16x8 v; } ah, al;
            {   // A: x fp32 from LDS (swizzled), split in-reg
                int rl = rg*32 + lo5;
                int xb = buf + 16384 + rl*128;
                int s0 = (ks*4 + hi*2)     ^ (rl & 7);
                int s1 = (ks*4 + hi*2 + 1) ^ (rl & 7);
                float4 q0 = *(const float4*)(smem + xb + s0*16);
                float4 q1 = *(const float4*)(smem + xb + s1*16);
                split2(q0.x, q0.y, ah.u[0], al.u[0]);
                split2(q0.z, q0.w, ah.u[1], al.u[1]);
                split2(q1.x, q1.y, ah.u[2], al.u[2]);
                split2(q1.z, q1.w, ah.u[3], al.u[3]);
            }
            bf16x8 bh[2], bl[2];
            #pragma unroll
            for (int ct = 0; ct < 2; ++ct) {
                int off = buf + (ks*2 + hi)*2048 + (cg*64 + ct*32 + lo5)*16;
                bh[ct] = *(const bf16x8*)(smem + off);
                bl[ct] = *(const bf16x8*)(smem + off + 8192);
            }
            #pragma unroll
            for (int ct = 0; ct < 2; ++ct) {
                acc[ct] = __builtin_amdgcn_mfma_f32_32x32x16_bf16(ah.v, bh[ct], acc[ct], 0, 0, 0);
                acc[ct] = __builtin_amdgcn_mfma_f32_32x32x16_bf16(ah.v, bl[ct], acc[ct], 0, 0, 0);
                acc[ct] = __builtin_amdgcn_mfma_f32_32x32x16_bf16(al.v, bh[ct], acc[ct], 0, 0, 0);
            }
        }
        __syncthreads();                           // buf(t+1) staged
    }

    // epilogue: tanh -> h@W2 partial -> butterfly over 32-lane half
    #pragma unroll
    for (int ct = 0; ct < 2; ++ct)
        #pragma unroll
        for (int e = 0; e < 16; ++e)
            acc[ct][e] = tanh_fast(acc[ct][e]);

    float4 w2v[2];
    #pragma unroll
    for (int ct = 0; ct < 2; ++ct)
        w2v[ct] = *(const float4*)(W2 + (size_t)(ch*128 + cg*64 + ct*32 + lo5) * NHEAD);

    float4 mine = make_float4(0.f, 0.f, 0.f, 0.f);
    #pragma unroll
    for (int e = 0; e < 16; ++e) {
        float s0 = 0.f, s1 = 0.f, s2 = 0.f, s3 = 0.f;
        #pragma unroll
        for (int ct = 0; ct < 2; ++ct) {
            float tv = acc[ct][e];
            s0 = fmaf(tv, w2v[ct].x, s0);
            s1 = fmaf(tv, w2v[ct].y, s1);
            s2 = fmaf(tv, w2v[ct].z, s2);
            s3 = fmaf(tv, w2v[ct].w, s3);
        }
        #pragma unroll
        for (int o = 16; o >= 1; o >>= 1) {        // halves stay separate
            s0 += __shfl_xor(s0, o, 64);
            s1 += __shfl_xor(s1, o, 64);
            s2 += __shfl_xor(s2, o, 64);
            s3 += __shfl_xor(s3, o, 64);
        }
        if (lo5 == e) mine = make_float4(s0, s1, s2, s3);
    }

    float (*p_lds)[RPB][4] = (float(*)[RPB][4])smem;   // [cg][row][4], 2 KiB
    if (lo5 < 16) {
        int myrow = rg*32 + (lo5 & 3) + 8*(lo5 >> 2) + 4*hi;
        *(float4*)p_lds[cg][myrow] = mine;
    }
    __syncthreads();
    if (tid < RPB) {
        int grow = blkrow + tid;
        if (grow < N) {
            float4 a0 = *(float4*)p_lds[0][tid];
            float4 a1 = *(float4*)p_lds[1][tid];
            float4 o;
            o.x = a0.x + a1.x; o.y = a0.y + a1.y;
            o.z = a0.z + a1.z; o.w = a0.w + a1.w;
            float* dst;
            if (ch == 0) {                         // lgA gets b2 folded in
                o.x += b2[0]; o.y += b2[1]; o.z += b2[2]; o.w += b2[3];
                dst = lgA;
            } else dst = lgB;
            *(float4*)(dst + (size_t)grow * NHEAD) = o;
        }
    }
}

// ---------------------------------------------------------------------------
__device__ __forceinline__ int lower_bound(const int* __restrict__ a, int n, int v) {
    int lo = 0, hi = n;
    while (lo < hi) { int m = (lo + hi) >> 1; if (a[m] < v) lo = m + 1; else hi = m; }
    return lo;
}

// ---------------------------------------------------------------------------
// K2: per-segment max & sum-of-exp of (lgA+lgB); stats -> out[b*256+0..7]
// ---------------------------------------------------------------------------
__global__ __launch_bounds__(256) void k2_seg(
    const int* __restrict__ batch, const float* __restrict__ lgA,
    const float* __restrict__ lgB, float* __restrict__ out, int N)
{
    const int b = blockIdx.x;
    const int tid = threadIdx.x;
    const int lane = tid & 63, wid = tid >> 6;
    const int start = lower_bound(batch, N, b);
    const int end   = lower_bound(batch, N, b + 1);
    const float4* la4 = (const float4*)lgA;
    const float4* lb4 = (const float4*)lgB;

    float4 mx = make_float4(-INFINITY, -INFINITY, -INFINITY, -INFINITY);
    for (int i = start + tid; i < end; i += 256) {
        float4 a = la4[i], bq = lb4[i];
        mx.x = fmaxf(mx.x, a.x + bq.x); mx.y = fmaxf(mx.y, a.y + bq.y);
        mx.z = fmaxf(mx.z, a.z + bq.z); mx.w = fmaxf(mx.w, a.w + bq.w);
    }
    #pragma unroll
    for (int ofs = 32; ofs >= 1; ofs >>= 1) {
        mx.x = fmaxf(mx.x, __shfl_xor(mx.x, ofs, 64));
        mx.y = fmaxf(mx.y, __shfl_xor(mx.y, ofs, 64));
        mx.z = fmaxf(mx.z, __shfl_xor(mx.z, ofs, 64));
        mx.w = fmaxf(mx.w, __shfl_xor(mx.w, ofs, 64));
    }
    __shared__ float4 red[4];
    if (lane == 0) red[wid] = mx;
    __syncthreads();
    float4 smax;
    smax.x = fmaxf(fmaxf(red[0].x, red[1].x), fmaxf(red[2].x, red[3].x));
    smax.y = fmaxf(fmaxf(red[0].y, red[1].y), fmaxf(red[2].y, red[3].y));
    smax.z = fmaxf(fmaxf(red[0].z, red[1].z), fmaxf(red[2].z, red[3].z));
    smax.w = fmaxf(fmaxf(red[0].w, red[1].w), fmaxf(red[2].w, red[3].w));
    __syncthreads();

    float4 sm = make_float4(0.f, 0.f, 0.f, 0.f);
    for (int i = start + tid; i < end; i += 256) {
        float4 a = la4[i], bq = lb4[i];
        sm.x += __expf(a.x + bq.x - smax.x); sm.y += __expf(a.y + bq.y - smax.y);
        sm.z += __expf(a.z + bq.z - smax.z); sm.w += __expf(a.w + bq.w - smax.w);
    }
    #pragma unroll
    for (int ofs = 32; ofs >= 1; ofs >>= 1) {
        sm.x += __shfl_xor(sm.x, ofs, 64);
        sm.y += __shfl_xor(sm.y, ofs, 64);
        sm.z += __shfl_xor(sm.z, ofs, 64);
        sm.w += __shfl_xor(sm.w, ofs, 64);
    }
    if (lane == 0) red[wid] = sm;
    __syncthreads();
    if (tid == 0) {
        float4 ssum;
        ssum.x = red[0].x + red[1].x + red[2].x + red[3].x;
        ssum.y = red[0].y + red[1].y + red[2].y + red[3].y;
        ssum.z = red[0].z + red[1].z + red[2].z + red[3].z;
        ssum.w = red[0].w + red[1].w + red[2].w + red[3].w;
        *(float4*)(out + (size_t)b * HD)     = smax;
        *(float4*)(out + (size_t)b * HD + 4) = ssum;
    }
}

// ---------------------------------------------------------------------------
// K3: attn = e/(sum+eps) (written over lgA = final attn out); z = sum attn*x;
//     graph_emb[b,:] = z @ Wt + (sum attn)*bt
// ---------------------------------------------------------------------------
__global__ __launch_bounds__(256) void k3_pool(
    const int* __restrict__ batch, const float* __restrict__ x,
    const float* __restrict__ Wt, const float* __restrict__ bt,
    const float* __restrict__ lgB, float* __restrict__ out, int N)
{
    const int b = blockIdx.x;
    const int tid = threadIdx.x;
    const int start = lower_bound(batch, N, b);
    const int end   = lower_bound(batch, N, b + 1);

    float4* at4 = (float4*)(out + (size_t)NSEG * HD);   // lgA now, attn after
    const float4* lb4 = (const float4*)lgB;

    const float4 smax = *(const float4*)(out + (size_t)b * HD);
    const float4 ssum = *(const float4*)(out + (size_t)b * HD + 4);
    float4 inv;
    inv.x = 1.0f / (ssum.x + 1e-16f); inv.y = 1.0f / (ssum.y + 1e-16f);
    inv.z = 1.0f / (ssum.z + 1e-16f); inv.w = 1.0f / (ssum.w + 1e-16f);

    float z0 = 0.f, z1 = 0.f, z2 = 0.f, z3 = 0.f;
    __shared__ float4 attn_s[256];

    for (int c0 = start; c0 < end; c0 += 256) {
        const int idx = c0 + tid;
        if (idx < end) {
            float4 l = at4[idx];
            float4 lb = lb4[idx];
            float4 a;
            a.x = __expf(l.x + lb.x - smax.x) * inv.x;
            a.y = __expf(l.y + lb.y - smax.y) * inv.y;
            a.z = __expf(l.z + lb.z - smax.z) * inv.z;
            a.w = __expf(l.w + lb.w - smax.w) * inv.w;
            at4[idx] = a;          // final attn output
            attn_s[tid] = a;
        }
        __syncthreads();
        const int cnt = min(256, end - c0);
        const float* xb = x + (size_t)c0 * HD + tid;
        #pragma unroll 4
        for (int i = 0; i < cnt; ++i) {
            float4 a = attn_s[i];
            float xv = xb[(size_t)i * HD];
            z0 = fmaf(a.x, xv, z0); z1 = fmaf(a.y, xv, z1);
            z2 = fmaf(a.z, xv, z2); z3 = fmaf(a.w, xv, z3);
        }
        __syncthreads();
    }

    __shared__ float zs[NHEAD][HD];
    zs[0][tid] = z0; zs[1][tid] = z1; zs[2][tid] = z2; zs[3][tid] = z3;
    __syncthreads();

    const int h = tid >> 6;                      // wave-uniform
    float smh, invh;
    if      (h == 0) { smh = ssum.x; invh = inv.x; }
    else if (h == 1) { smh = ssum.y; invh = inv.y; }
    else if (h == 2) { smh = ssum.z; invh = inv.z; }
    else             { smh = ssum.w; invh = inv.w; }

    float acc = smh * invh * bt[tid];            // (sum attn_h) * bt[j]
    #pragma unroll 4
    for (int k = 0; k < HD; ++k)
        acc = fmaf(zs[h][k], Wt[(size_t)k * HD + tid], acc);

    out[(size_t)b * HD + tid] = acc;             // overwrites stats stash: ok
}

// ---------------------------------------------------------------------------
extern "C" void kernel_launch(void* const* d_in, const int* in_sizes, int n_in,
                              void* d_out, int out_size, void* d_ws, size_t ws_size,
                              hipStream_t stream) {
    const float* x   = (const float*)d_in[0];
    const int*   bat = (const int*)  d_in[1];
    const float* W1  = (const float*)d_in[2];
    const float* b1  = (const float*)d_in[3];
    const float* W2  = (const float*)d_in[4];
    const float* b2  = (const float*)d_in[5];
    const float* Wt  = (const float*)d_in[6];
    const float* bt  = (const float*)d_in[7];
    float* out = (float*)d_out;
    const int N = in_sizes[0] / HD;

    float* lgA = out + (size_t)NSEG * HD;          // attn region of d_out
    char*  wsW = (char*)d_ws;                      // [0,256K): split W planes
    float* lgB = (float*)((char*)d_ws + 262144);   // [256K,+6.4M): partial logits

    hipLaunchKernelGGL(k0_prep, dim3(128), dim3(256), 0, stream, W1, wsW);
    hipLaunchKernelGGL(k1_mfma, dim3(((NRB64 + 7) / 8) * 16), dim3(K1_THREADS),
                       K1_LDS, stream, x, wsW, b1, W2, b2, lgA, lgB, N);
    hipLaunchKernelGGL(k2_seg, dim3(NSEG), dim3(256), 0, stream, bat, lgA, lgB, out, N);
    hipLaunchKernelGGL(k3_pool, dim3(NSEG), dim3(256), 0, stream, bat, x, Wt, bt, lgB, out, N);
}

// Round 11
// 383.800 us; speedup vs baseline: 1.1741x; 1.1741x over previous
//
#include <hip/hip_runtime.h>
#include <math.h>

#define HD    256
#define NHEAD 4
#define NSEG  1024
#define RPB   64                                    // rows per block
#define NRB64 6250                                  // 400000/64 row slabs

typedef short bf16x8 __attribute__((ext_vector_type(8)));
typedef float f32x16 __attribute__((ext_vector_type(16)));

__device__ __forceinline__ float tanh_fast(float v) {
    float e = __expf(2.0f * v);                    // overflow->inf, tanh->1: ok
    return 1.0f - 2.0f * __builtin_amdgcn_rcpf(e + 1.0f);
}

// split fp32 pair into packed bf16-hi word and bf16-lo word (truncation split;
// lo captures mantissa bits 9..17 -> per-product rel err ~2^-17)
__device__ __forceinline__ void split2(float a, float b, unsigned &hi, unsigned &lo) {
    unsigned ba = __float_as_uint(a), bb = __float_as_uint(b);
    unsigned ha = ba & 0xFFFF0000u, hb = bb & 0xFFFF0000u;
    float la = a - __uint_as_float(ha);
    float lb = b - __uint_as_float(hb);
    hi = (ha >> 16) | hb;
    lo = (__float_as_uint(la) >> 16) | (__float_as_uint(lb) & 0xFFFF0000u);
}

__device__ __forceinline__ void gld16(const void* g, void* l) {
    __builtin_amdgcn_global_load_lds(
        (const __attribute__((address_space(1))) void*)g,
        (__attribute__((address_space(3))) void*)l, 16, 0, 0);
}

// ---------------------------------------------------------------------------
// k0_prep: W1 (fp32 [k][c]) -> ws split-bf16 planes laid out exactly as k1's
// per-chunk LDS image: off = t*32768 + ch*16384 + o*2048 + c*16 + j*4
// (hi plane +0, lo plane +8192 within the ch region). 256 KiB total.
// ---------------------------------------------------------------------------
__global__ __launch_bounds__(256) void k0_prep(
    const float* __restrict__ W1, char* __restrict__ ws)
{
    int g = blockIdx.x * 256 + threadIdx.x;        // 32768 threads
    int c  = g & 127;
    int j  = (g >> 7) & 3;
    int o  = (g >> 9) & 3;
    int ch = (g >> 11) & 1;
    int t  = g >> 12;
    int k   = t*32 + o*8 + 2*j;
    int col = ch*128 + c;
    float a = W1[(size_t)k * HD + col];
    float b = W1[(size_t)(k + 1) * HD + col];
    unsigned hw, lw;
    split2(a, b, hw, lw);
    size_t off = (size_t)t*32768 + ch*16384 + o*2048 + c*16 + j*4;
    *(unsigned*)(ws + off)        = hw;
    *(unsigned*)(ws + off + 8192) = lw;
}

// ---------------------------------------------------------------------------
// K1: partial logits for one 128-col half.
// 256 thr = 4 waves: rg=wid>>1 (2 x 32 rows), cg=wid&1 (2 x 64 cols);
// wave tile 32x64 = 2 x 32x32 mfma, acc = 32 AGPR.
// SYNC STRUCTURE (replay-proven R5/R6/R8): per chunk, issue STAGE(t+1) into
// the other buffer FIRST (loads fly under compute), compute chunk t, then
// __syncthreads() (vmcnt+lgkm drain + barrier). No raw s_barrier anywhere —
// R9/R10's counted-vmcnt raw-barrier schedule raced under replay.
// 2 buffers x 24KB ([W 16K][x 8K]) = 48KB -> 3 blocks/CU.
// x image: row-major [64 rows][128B] with source-side slot^=(row&7) swizzle
// (coalesced HBM reads) and matching read-side XOR (conflict-free ds_read).
// Epilogue: tanh -> h split-bf16 planes in LDS -> h@W2 via 24 MFMA -> D
// scatter (replaces the 320-op shuffle butterfly; all __syncthreads).
// ---------------------------------------------------------------------------
#define K1_THREADS 256
#define BUFB 24576
#define K1_LDS (2*BUFB)

__global__ __launch_bounds__(K1_THREADS, 3) void k1_mfma(
    const float* __restrict__ x, const char* __restrict__ wsW,
    const float* __restrict__ b1, const float* __restrict__ W2,
    const float* __restrict__ b2, float* __restrict__ lgA,
    float* __restrict__ lgB, int N)
{
    extern __shared__ __align__(16) char smem[];

    const int raw = blockIdx.x;
    const int ch  = (raw >> 3) & 1;
    const int rb  = (raw >> 4) * 8 + (raw & 7);
    if (rb >= NRB64) return;

    const int tid  = threadIdx.x;
    const int lane = tid & 63;
    const int lo5  = lane & 31;
    const int hi   = lane >> 5;
    const int wid  = tid >> 6;
    const int rg   = wid >> 1;                     // 0..1 (32-row groups)
    const int cg   = wid & 1;                      // 0..1 (64-col groups)
    const int blkrow = rb * RPB;
    const int rl   = rg*32 + lo5;                  // local row this lane computes

    f32x16 acc[2];
    #pragma unroll
    for (int ct = 0; ct < 2; ++ct) {
        float b1v = b1[ch*128 + cg*64 + ct*32 + lo5];
        #pragma unroll
        for (int e = 0; e < 16; ++e) acc[ct][e] = b1v;
    }

    // stage sources. W: linear from pre-split ws. x: row-major [row][slot]
    // LDS image, source slot pre-swizzled (slot ^ row&7) so the linear
    // wave-uniform-base+lane*16 LDS write lands the swizzled image; 8 lanes
    // per 128B row -> coalesced global segments.
    const char* gwbase = wsW + ch*16384 + tid*16;
    const char* gxbase[2];
    #pragma unroll
    for (int i = 0; i < 2; ++i) {
        int idx  = i*256 + tid;
        int row  = idx >> 3;                       // 0..63
        int slot = idx & 7;
        long grow = blkrow + row; if (grow > N-1) grow = N-1;
        gxbase[i] = (const char*)x + grow*1024 + ((slot ^ (row & 7)) * 16);
    }

    auto STAGE = [&](int u) {                      // u uniform (unrolled const)
        const int db = (u & 1) * BUFB;
        const char* w = gwbase + (size_t)u*32768;
        #pragma unroll
        for (int i = 0; i < 4; ++i)
            gld16(w + i*4096, smem + db + i*4096 + tid*16);
        #pragma unroll
        for (int i = 0; i < 2; ++i)
            gld16(gxbase[i] + (size_t)u*128, smem + db + 16384 + i*4096 + tid*16);
    };

    STAGE(0);
    __syncthreads();                               // chunk 0 landed

    #pragma unroll
    for (int t = 0; t < 8; ++t) {
        if (t < 7) STAGE(t + 1);                   // fly under compute
        const int buf = (t & 1) * BUFB;
        #pragma unroll
        for (int ks = 0; ks < 2; ++ks) {
            union { unsigned u[4]; bf16x8 v; } ah, al;
            {   // A: x fp32 rows from LDS, read-side slot XOR, split in-reg
                const int s0 = ks*4 + hi*2;
                const int xb = buf + 16384 + rl*128;
                float4 q0 = *(const float4*)(smem + xb + ((s0     ^ (rl & 7)) << 4));
                float4 q1 = *(const float4*)(smem + xb + (((s0+1) ^ (rl & 7)) << 4));
                split2(q0.x, q0.y, ah.u[0], al.u[0]);
                split2(q0.z, q0.w, ah.u[1], al.u[1]);
                split2(q1.x, q1.y, ah.u[2], al.u[2]);
                split2(q1.z, q1.w, ah.u[3], al.u[3]);
            }
            bf16x8 bh[2], bl[2];
            #pragma unroll
            for (int ct = 0; ct < 2; ++ct) {
                int off = buf + (ks*2 + hi)*2048 + (cg*64 + ct*32 + lo5)*16;
                bh[ct] = *(const bf16x8*)(smem + off);
                bl[ct] = *(const bf16x8*)(smem + off + 8192);
            }
            #pragma unroll
            for (int ct = 0; ct < 2; ++ct) {
                acc[ct] = __builtin_amdgcn_mfma_f32_32x32x16_bf16(ah.v, bh[ct], acc[ct], 0, 0, 0);
                acc[ct] = __builtin_amdgcn_mfma_f32_32x32x16_bf16(ah.v, bl[ct], acc[ct], 0, 0, 0);
                acc[ct] = __builtin_amdgcn_mfma_f32_32x32x16_bf16(al.v, bh[ct], acc[ct], 0, 0, 0);
            }
        }
        __syncthreads();                           // drain stage(t+1) + reuse guard
    }

    // ---- epilogue: tanh -> h planes (split bf16, swizzled [row][col]) ------
    // hi plane [0,16K), lo plane [16K,32K); p_lds fp32[64][4] at 32K.
    #pragma unroll
    for (int ct = 0; ct < 2; ++ct) {
        const int col = cg*64 + ct*32 + lo5;
        #pragma unroll
        for (int e = 0; e < 16; ++e) {
            float h = tanh_fast(acc[ct][e]);
            int row = rg*32 + (e & 3) + 8*(e >> 2) + 4*hi;
            unsigned hh = __float_as_uint(h) & 0xFFFF0000u;
            float hl = h - __uint_as_float(hh);
            int byte = row*256 + ((((col >> 3) ^ (row & 15))) << 4) + (col & 7)*2;
            *(unsigned short*)(smem + byte)         = (unsigned short)(hh >> 16);
            *(unsigned short*)(smem + 16384 + byte) = (unsigned short)(__float_as_uint(hl) >> 16);
        }
    }
    __syncthreads();

    float* p_lds = (float*)(smem + 32768);         // [64][4]
    if (wid < 2) {                                 // waves 0,1: rt = wid
        const int rt  = wid;
        const int row = rt*32 + lo5;               // A-row this lane reads
        const int colh = lo5 & 3;
        const bool act = lo5 < 4;
        f32x16 d;
        #pragma unroll
        for (int e = 0; e < 16; ++e) d[e] = 0.0f;
        #pragma unroll
        for (int kk = 0; kk < 8; ++kk) {
            int sb = row*256 + (((kk*2 + hi) ^ (row & 15)) << 4);
            bf16x8 ahh = *(const bf16x8*)(smem + sb);
            bf16x8 alo = *(const bf16x8*)(smem + 16384 + sb);
            union { unsigned short s[8]; bf16x8 v; } wh, wl;
            #pragma unroll
            for (int j = 0; j < 8; ++j) {
                float w = W2[(size_t)(ch*128 + kk*16 + hi*8 + j)*NHEAD + colh];
                w = act ? w : 0.0f;
                unsigned hb = __float_as_uint(w) & 0xFFFF0000u;
                float wlf = w - __uint_as_float(hb);
                wh.s[j] = (unsigned short)(hb >> 16);
                wl.s[j] = (unsigned short)(__float_as_uint(wlf) >> 16);
            }
            d = __builtin_amdgcn_mfma_f32_32x32x16_bf16(ahh, wh.v, d, 0, 0, 0);
            d = __builtin_amdgcn_mfma_f32_32x32x16_bf16(ahh, wl.v, d, 0, 0, 0);
            d = __builtin_amdgcn_mfma_f32_32x32x16_bf16(alo, wh.v, d, 0, 0, 0);
        }
        if (act) {                                 // D scatter by C-layout
            #pragma unroll
            for (int e = 0; e < 16; ++e) {
                int r = rt*32 + (e & 3) + 8*(e >> 2) + 4*hi;
                p_lds[r*4 + lo5] = d[e];
            }
        }
    }
    __syncthreads();
    if (tid < RPB) {
        int grow = blkrow + tid;
        if (grow < N) {
            float4 o = *(float4*)(p_lds + tid*4);
            float* dst;
            if (ch == 0) {
                o.x += b2[0]; o.y += b2[1]; o.z += b2[2]; o.w += b2[3];
                dst = lgA;
            } else dst = lgB;
            *(float4*)(dst + (size_t)grow * NHEAD) = o;
        }
    }
}

// ---------------------------------------------------------------------------
__device__ __forceinline__ int lower_bound(const int* __restrict__ a, int n, int v) {
    int lo = 0, hi = n;
    while (lo < hi) { int m = (lo + hi) >> 1; if (a[m] < v) lo = m + 1; else hi = m; }
    return lo;
}

// ---------------------------------------------------------------------------
// K2: per-segment max & sum-of-exp of (lgA+lgB); stats -> out[b*256+0..7]
// ---------------------------------------------------------------------------
__global__ __launch_bounds__(256) void k2_seg(
    const int* __restrict__ batch, const float* __restrict__ lgA,
    const float* __restrict__ lgB, float* __restrict__ out, int N)
{
    const int b = blockIdx.x;
    const int tid = threadIdx.x;
    const int lane = tid & 63, wid = tid >> 6;
    const int start = lower_bound(batch, N, b);
    const int end   = lower_bound(batch, N, b + 1);
    const float4* la4 = (const float4*)lgA;
    const float4* lb4 = (const float4*)lgB;

    float4 mx = make_float4(-INFINITY, -INFINITY, -INFINITY, -INFINITY);
    for (int i = start + tid; i < end; i += 256) {
        float4 a = la4[i], bq = lb4[i];
        mx.x = fmaxf(mx.x, a.x + bq.x); mx.y = fmaxf(mx.y, a.y + bq.y);
        mx.z = fmaxf(mx.z, a.z + bq.z); mx.w = fmaxf(mx.w, a.w + bq.w);
    }
    #pragma unroll
    for (int ofs = 32; ofs >= 1; ofs >>= 1) {
        mx.x = fmaxf(mx.x, __shfl_xor(mx.x, ofs, 64));
        mx.y = fmaxf(mx.y, __shfl_xor(mx.y, ofs, 64));
        mx.z = fmaxf(mx.z, __shfl_xor(mx.z, ofs, 64));
        mx.w = fmaxf(mx.w, __shfl_xor(mx.w, ofs, 64));
    }
    __shared__ float4 red[4];
    if (lane == 0) red[wid] = mx;
    __syncthreads();
    float4 smax;
    smax.x = fmaxf(fmaxf(red[0].x, red[1].x), fmaxf(red[2].x, red[3].x));
    smax.y = fmaxf(fmaxf(red[0].y, red[1].y), fmaxf(red[2].y, red[3].y));
    smax.z = fmaxf(fmaxf(red[0].z, red[1].z), fmaxf(red[2].z, red[3].z));
    smax.w = fmaxf(fmaxf(red[0].w, red[1].w), fmaxf(red[2].w, red[3].w));
    __syncthreads();

    float4 sm = make_float4(0.f, 0.f, 0.f, 0.f);
    for (int i = start + tid; i < end; i += 256) {
        float4 a = la4[i], bq = lb4[i];
        sm.x += __expf(a.x + bq.x - smax.x); sm.y += __expf(a.y + bq.y - smax.y);
        sm.z += __expf(a.z + bq.z - smax.z); sm.w += __expf(a.w + bq.w - smax.w);
    }
    #pragma unroll
    for (int ofs = 32; ofs >= 1; ofs >>= 1) {
        sm.x += __shfl_xor(sm.x, ofs, 64);
        sm.y += __shfl_xor(sm.y, ofs, 64);
        sm.z += __shfl_xor(sm.z, ofs, 64);
        sm.w += __shfl_xor(sm.w, ofs, 64);
    }
    if (lane == 0) red[wid] = sm;
    __syncthreads();
    if (tid == 0) {
        float4 ssum;
        ssum.x = red[0].x + red[1].x + red[2].x + red[3].x;
        ssum.y = red[0].y + red[1].y + red[2].y + red[3].y;
        ssum.z = red[0].z + red[1].z + red[2].z + red[3].z;
        ssum.w = red[0].w + red[1].w + red[2].w + red[3].w;
        *(float4*)(out + (size_t)b * HD)     = smax;
        *(float4*)(out + (size_t)b * HD + 4) = ssum;
    }
}

// ---------------------------------------------------------------------------
// K3: attn = e/(sum+eps) (written over lgA = final attn out); z = sum attn*x;
//     graph_emb[b,:] = z @ Wt + (sum attn)*bt
// ---------------------------------------------------------------------------
__global__ __launch_bounds__(256) void k3_pool(
    const int* __restrict__ batch, const float* __restrict__ x,
    const float* __restrict__ Wt, const float* __restrict__ bt,
    const float* __restrict__ lgB, float* __restrict__ out, int N)
{
    const int b = blockIdx.x;
    const int tid = threadIdx.x;
    const int start = lower_bound(batch, N, b);
    const int end   = lower_bound(batch, N, b + 1);

    float4* at4 = (float4*)(out + (size_t)NSEG * HD);   // lgA now, attn after
    const float4* lb4 = (const float4*)lgB;

    const float4 smax = *(const float4*)(out + (size_t)b * HD);
    const float4 ssum = *(const float4*)(out + (size_t)b * HD + 4);
    float4 inv;
    inv.x = 1.0f / (ssum.x + 1e-16f); inv.y = 1.0f / (ssum.y + 1e-16f);
    inv.z = 1.0f / (ssum.z + 1e-16f); inv.w = 1.0f / (ssum.w + 1e-16f);

    float z0 = 0.f, z1 = 0.f, z2 = 0.f, z3 = 0.f;
    __shared__ float4 attn_s[256];

    for (int c0 = start; c0 < end; c0 += 256) {
        const int idx = c0 + tid;
        if (idx < end) {
            float4 l = at4[idx];
            float4 lb = lb4[idx];
            float4 a;
            a.x = __expf(l.x + lb.x - smax.x) * inv.x;
            a.y = __expf(l.y + lb.y - smax.y) * inv.y;
            a.z = __expf(l.z + lb.z - smax.z) * inv.z;
            a.w = __expf(l.w + lb.w - smax.w) * inv.w;
            at4[idx] = a;          // final attn output
            attn_s[tid] = a;
        }
        __syncthreads();
        const int cnt = min(256, end - c0);
        const float* xb = x + (size_t)c0 * HD + tid;
        #pragma unroll 4
        for (int i = 0; i < cnt; ++i) {
            float4 a = attn_s[i];
            float xv = xb[(size_t)i * HD];
            z0 = fmaf(a.x, xv, z0); z1 = fmaf(a.y, xv, z1);
            z2 = fmaf(a.z, xv, z2); z3 = fmaf(a.w, xv, z3);
        }
        __syncthreads();
    }

    __shared__ float zs[NHEAD][HD];
    zs[0][tid] = z0; zs[1][tid] = z1; zs[2][tid] = z2; zs[3][tid] = z3;
    __syncthreads();

    const int h = tid >> 6;                      // wave-uniform
    float smh, invh;
    if      (h == 0) { smh = ssum.x; invh = inv.x; }
    else if (h == 1) { smh = ssum.y; invh = inv.y; }
    else if (h == 2) { smh = ssum.z; invh = inv.z; }
    else             { smh = ssum.w; invh = inv.w; }

    float acc = smh * invh * bt[tid];            // (sum attn_h) * bt[j]
    #pragma unroll 4
    for (int k = 0; k < HD; ++k)
        acc = fmaf(zs[h][k], Wt[(size_t)k * HD + tid], acc);

    out[(size_t)b * HD + tid] = acc;             // overwrites stats stash: ok
}

// ---------------------------------------------------------------------------
extern "C" void kernel_launch(void* const* d_in, const int* in_sizes, int n_in,
                              void* d_out, int out_size, void* d_ws, size_t ws_size,
                              hipStream_t stream) {
    const float* x   = (const float*)d_in[0];
    const int*   bat = (const int*)  d_in[1];
    const float* W1  = (const float*)d_in[2];
    const float* b1  = (const float*)d_in[3];
    const float* W2  = (const float*)d_in[4];
    const float* b2  = (const float*)d_in[5];
    const float* Wt  = (const float*)d_in[6];
    const float* bt  = (const float*)d_in[7];
    float* out = (float*)d_out;
    const int N = in_sizes[0] / HD;

    float* lgA = out + (size_t)NSEG * HD;          // attn region of d_out
    char*  wsW = (char*)d_ws;                      // [0,256K): split W planes
    float* lgB = (float*)((char*)d_ws + 262144);   // [256K,+6.4M): partial logits

    hipLaunchKernelGGL(k0_prep, dim3(128), dim3(256), 0, stream, W1, wsW);
    hipLaunchKernelGGL(k1_mfma, dim3(((NRB64 + 7) / 8) * 16), dim3(K1_THREADS),
                       K1_LDS, stream, x, wsW, b1, W2, b2, lgA, lgB, N);
    hipLaunchKernelGGL(k2_seg, dim3(NSEG), dim3(256), 0, stream, bat, lgA, lgB, out, N);
    hipLaunchKernelGGL(k3_pool, dim3(NSEG), dim3(256), 0, stream, bat, x, Wt, bt, lgB, out, N);
}

// Round 12
// 372.876 us; speedup vs baseline: 1.2085x; 1.0293x over previous
//
#include <hip/hip_runtime.h>
#include <math.h>

#define HD    256
#define NHEAD 4
#define NSEG  1024
#define RPB   64                                    // rows per block
#define NRB64 6250                                  // 400000/64 row slabs

typedef short bf16x8 __attribute__((ext_vector_type(8)));
typedef float f32x16 __attribute__((ext_vector_type(16)));

__device__ __forceinline__ float tanh_fast(float v) {
    float e = __expf(2.0f * v);                    // overflow->inf, tanh->1: ok
    return 1.0f - 2.0f * __builtin_amdgcn_rcpf(e + 1.0f);
}

// split fp32 pair into packed bf16-hi word and bf16-lo word (truncation split;
// lo captures mantissa bits 9..17 -> per-product rel err ~2^-17)
__device__ __forceinline__ void split2(float a, float b, unsigned &hi, unsigned &lo) {
    unsigned ba = __float_as_uint(a), bb = __float_as_uint(b);
    unsigned ha = ba & 0xFFFF0000u, hb = bb & 0xFFFF0000u;
    float la = a - __uint_as_float(ha);
    float lb = b - __uint_as_float(hb);
    hi = (ha >> 16) | hb;
    lo = (__float_as_uint(la) >> 16) | (__float_as_uint(lb) & 0xFFFF0000u);
}

__device__ __forceinline__ void gld16(const void* g, void* l) {
    __builtin_amdgcn_global_load_lds(
        (const __attribute__((address_space(1))) void*)g,
        (__attribute__((address_space(3))) void*)l, 16, 0, 0);
}

// ---------------------------------------------------------------------------
// k0_prep: W1 (fp32 [k][c]) -> ws split-bf16 planes laid out exactly as k1's
// per-chunk LDS image, KC=16: chunk t (k in [16t,16t+16)):
//   off = t*16384 + ch*8192 + o*2048 + c*16 + j*4   (hi plane; lo at +4096)
// with o = k_local>>3, c = col within 128-col half, j = k-pair. 256 KiB total.
// ---------------------------------------------------------------------------
__global__ __launch_bounds__(256) void k0_prep(
    const float* __restrict__ W1, char* __restrict__ ws)
{
    int g = blockIdx.x * 256 + threadIdx.x;        // 32768 threads
    int c  = g & 127;
    int j  = (g >> 7) & 3;
    int o  = (g >> 9) & 1;
    int ch = (g >> 10) & 1;
    int t  = g >> 11;                              // 0..15
    int k   = t*16 + o*8 + 2*j;
    int col = ch*128 + c;
    float a = W1[(size_t)k * HD + col];
    float b = W1[(size_t)(k + 1) * HD + col];
    unsigned hw, lw;
    split2(a, b, hw, lw);
    size_t off = (size_t)t*16384 + ch*8192 + o*2048 + c*16 + j*4;
    *(unsigned*)(ws + off)        = hw;
    *(unsigned*)(ws + off + 4096) = lw;
}

// ---------------------------------------------------------------------------
// K1: partial logits for one 128-col half.
// 256 thr = 4 waves: rg=wid>>1 (2 x 32 rows), cg=wid&1 (2 x 64 cols);
// wave tile 32x64 = 2 x 32x32 mfma, acc = 32 AGPR.
// SYNC STRUCTURE (replay-proven R5/R6/R8/R11): per chunk, issue STAGE(t+1)
// into the other buffer FIRST (loads fly under compute), compute chunk t,
// then __syncthreads(). No raw s_barrier anywhere (R10 raced under replay).
// KC=16: buffer = [W 8K][x 4K] = 12KB x2 = 24KB staging; epilogue needs 33KB
// -> LDS 33KB -> 4 blocks/CU, 16 waves/CU (R11 was 3 blocks; stall-bound).
// x image: row-major [64 rows][64B=4 slots] with source-side slot^=(row&3)
// swizzle; adjacent chunk reads the other half of each 128B line (L2 hit).
// Epilogue: tanh -> h split-bf16 planes in LDS -> h@W2 via 24 MFMA -> D
// scatter (all __syncthreads; unchanged from R11-PASS).
// ---------------------------------------------------------------------------
#define K1_THREADS 256
#define BUFB 12288
#define K1_LDS 33792

__global__ __launch_bounds__(K1_THREADS, 4) void k1_mfma(
    const float* __restrict__ x, const char* __restrict__ wsW,
    const float* __restrict__ b1, const float* __restrict__ W2,
    const float* __restrict__ b2, float* __restrict__ lgA,
    float* __restrict__ lgB, int N)
{
    extern __shared__ __align__(16) char smem[];

    const int raw = blockIdx.x;
    const int ch  = (raw >> 3) & 1;
    const int rb  = (raw >> 4) * 8 + (raw & 7);
    if (rb >= NRB64) return;

    const int tid  = threadIdx.x;
    const int lane = tid & 63;
    const int lo5  = lane & 31;
    const int hi   = lane >> 5;
    const int wid  = tid >> 6;
    const int rg   = wid >> 1;                     // 0..1 (32-row groups)
    const int cg   = wid & 1;                      // 0..1 (64-col groups)
    const int blkrow = rb * RPB;
    const int rl   = rg*32 + lo5;                  // local row this lane computes

    f32x16 acc[2];
    #pragma unroll
    for (int ct = 0; ct < 2; ++ct) {
        float b1v = b1[ch*128 + cg*64 + ct*32 + lo5];
        #pragma unroll
        for (int e = 0; e < 16; ++e) acc[ct][e] = b1v;
    }

    // stage sources. W: linear from pre-split ws (2 x 16B per thread).
    // x: row-major [row][slot] image, slot pre-swizzled (slot ^ row&3) on the
    // global side so the linear LDS write lands the swizzled image.
    const char* gwbase = wsW + ch*8192 + tid*16;   // + u*16384 per chunk
    const char* gxbase;
    {
        int row  = tid >> 2;                       // 0..63
        int slot = tid & 3;
        long grow = blkrow + row; if (grow > N-1) grow = N-1;
        gxbase = (const char*)x + grow*1024 + ((slot ^ (row & 3)) * 16);
    }

    auto STAGE = [&](int u) {                      // u uniform (unrolled const)
        const int db = (u & 1) * BUFB;
        const char* w = gwbase + (size_t)u*16384;
        #pragma unroll
        for (int i = 0; i < 2; ++i)
            gld16(w + i*4096, smem + db + i*4096 + tid*16);
        gld16(gxbase + (size_t)u*64, smem + db + 8192 + tid*16);
    };

    STAGE(0);
    __syncthreads();                               // chunk 0 landed

    #pragma unroll
    for (int t = 0; t < 16; ++t) {
        if (t < 15) STAGE(t + 1);                  // fly under compute
        const int buf = (t & 1) * BUFB;
        {
            union { unsigned u[4]; bf16x8 v; } ah, al;
            {   // A: x fp32 rows from LDS, read-side slot XOR, split in-reg
                const int s0 = hi*2;
                const int xb = buf + 8192 + rl*64;
                float4 q0 = *(const float4*)(smem + xb + ((s0     ^ (rl & 3)) << 4));
                float4 q1 = *(const float4*)(smem + xb + (((s0+1) ^ (rl & 3)) << 4));
                split2(q0.x, q0.y, ah.u[0], al.u[0]);
                split2(q0.z, q0.w, ah.u[1], al.u[1]);
                split2(q1.x, q1.y, ah.u[2], al.u[2]);
                split2(q1.z, q1.w, ah.u[3], al.u[3]);
            }
            bf16x8 bh[2], bl[2];
            #pragma unroll
            for (int ct = 0; ct < 2; ++ct) {
                int off = buf + hi*2048 + (cg*64 + ct*32 + lo5)*16;
                bh[ct] = *(const bf16x8*)(smem + off);
                bl[ct] = *(const bf16x8*)(smem + off + 4096);
            }
            #pragma unroll
            for (int ct = 0; ct < 2; ++ct) {
                acc[ct] = __builtin_amdgcn_mfma_f32_32x32x16_bf16(ah.v, bh[ct], acc[ct], 0, 0, 0);
                acc[ct] = __builtin_amdgcn_mfma_f32_32x32x16_bf16(ah.v, bl[ct], acc[ct], 0, 0, 0);
                acc[ct] = __builtin_amdgcn_mfma_f32_32x32x16_bf16(al.v, bh[ct], acc[ct], 0, 0, 0);
            }
        }
        __syncthreads();                           // drain stage(t+1) + reuse guard
    }

    // ---- epilogue: tanh -> h planes (split bf16, swizzled [row][col]) ------
    // hi plane [0,16K), lo plane [16K,32K); p_lds fp32[64][4] at 32K.
    #pragma unroll
    for (int ct = 0; ct < 2; ++ct) {
        const int col = cg*64 + ct*32 + lo5;
        #pragma unroll
        for (int e = 0; e < 16; ++e) {
            float h = tanh_fast(acc[ct][e]);
            int row = rg*32 + (e & 3) + 8*(e >> 2) + 4*hi;
            unsigned hh = __float_as_uint(h) & 0xFFFF0000u;
            float hl = h - __uint_as_float(hh);
            int byte = row*256 + ((((col >> 3) ^ (row & 15))) << 4) + (col & 7)*2;
            *(unsigned short*)(smem + byte)         = (unsigned short)(hh >> 16);
            *(unsigned short*)(smem + 16384 + byte) = (unsigned short)(__float_as_uint(hl) >> 16);
        }
    }
    __syncthreads();

    float* p_lds = (float*)(smem + 32768);         // [64][4]
    if (wid < 2) {                                 // waves 0,1: rt = wid
        const int rt  = wid;
        const int row = rt*32 + lo5;               // A-row this lane reads
        const int colh = lo5 & 3;
        const bool act = lo5 < 4;
        f32x16 d;
        #pragma unroll
        for (int e = 0; e < 16; ++e) d[e] = 0.0f;
        #pragma unroll
        for (int kk = 0; kk < 8; ++kk) {
            int sb = row*256 + (((kk*2 + hi) ^ (row & 15)) << 4);
            bf16x8 ahh = *(const bf16x8*)(smem + sb);
            bf16x8 alo = *(const bf16x8*)(smem + 16384 + sb);
            union { unsigned short s[8]; bf16x8 v; } wh, wl;
            #pragma unroll
            for (int j = 0; j < 8; ++j) {
                float w = W2[(size_t)(ch*128 + kk*16 + hi*8 + j)*NHEAD + colh];
                w = act ? w : 0.0f;
                unsigned hb = __float_as_uint(w) & 0xFFFF0000u;
                float wlf = w - __uint_as_float(hb);
                wh.s[j] = (unsigned short)(hb >> 16);
                wl.s[j] = (unsigned short)(__float_as_uint(wlf) >> 16);
            }
            d = __builtin_amdgcn_mfma_f32_32x32x16_bf16(ahh, wh.v, d, 0, 0, 0);
            d = __builtin_amdgcn_mfma_f32_32x32x16_bf16(ahh, wl.v, d, 0, 0, 0);
            d = __builtin_amdgcn_mfma_f32_32x32x16_bf16(alo, wh.v, d, 0, 0, 0);
        }
        if (act) {                                 // D scatter by C-layout
            #pragma unroll
            for (int e = 0; e < 16; ++e) {
                int r = rt*32 + (e & 3) + 8*(e >> 2) + 4*hi;
                p_lds[r*4 + lo5] = d[e];
            }
        }
    }
    __syncthreads();
    if (tid < RPB) {
        int grow = blkrow + tid;
        if (grow < N) {
            float4 o = *(float4*)(p_lds + tid*4);
            float* dst;
            if (ch == 0) {
                o.x += b2[0]; o.y += b2[1]; o.z += b2[2]; o.w += b2[3];
                dst = lgA;
            } else dst = lgB;
            *(float4*)(dst + (size_t)grow * NHEAD) = o;
        }
    }
}

// ---------------------------------------------------------------------------
__device__ __forceinline__ int lower_bound(const int* __restrict__ a, int n, int v) {
    int lo = 0, hi = n;
    while (lo < hi) { int m = (lo + hi) >> 1; if (a[m] < v) lo = m + 1; else hi = m; }
    return lo;
}

// ---------------------------------------------------------------------------
// K2: per-segment max & sum-of-exp of (lgA+lgB); stats -> out[b*256+0..7]
// ---------------------------------------------------------------------------
__global__ __launch_bounds__(256) void k2_seg(
    const int* __restrict__ batch, const float* __restrict__ lgA,
    const float* __restrict__ lgB, float* __restrict__ out, int N)
{
    const int b = blockIdx.x;
    const int tid = threadIdx.x;
    const int lane = tid & 63, wid = tid >> 6;
    const int start = lower_bound(batch, N, b);
    const int end   = lower_bound(batch, N, b + 1);
    const float4* la4 = (const float4*)lgA;
    const float4* lb4 = (const float4*)lgB;

    float4 mx = make_float4(-INFINITY, -INFINITY, -INFINITY, -INFINITY);
    for (int i = start + tid; i < end; i += 256) {
        float4 a = la4[i], bq = lb4[i];
        mx.x = fmaxf(mx.x, a.x + bq.x); mx.y = fmaxf(mx.y, a.y + bq.y);
        mx.z = fmaxf(mx.z, a.z + bq.z); mx.w = fmaxf(mx.w, a.w + bq.w);
    }
    #pragma unroll
    for (int ofs = 32; ofs >= 1; ofs >>= 1) {
        mx.x = fmaxf(mx.x, __shfl_xor(mx.x, ofs, 64));
        mx.y = fmaxf(mx.y, __shfl_xor(mx.y, ofs, 64));
        mx.z = fmaxf(mx.z, __shfl_xor(mx.z, ofs, 64));
        mx.w = fmaxf(mx.w, __shfl_xor(mx.w, ofs, 64));
    }
    __shared__ float4 red[4];
    if (lane == 0) red[wid] = mx;
    __syncthreads();
    float4 smax;
    smax.x = fmaxf(fmaxf(red[0].x, red[1].x), fmaxf(red[2].x, red[3].x));
    smax.y = fmaxf(fmaxf(red[0].y, red[1].y), fmaxf(red[2].y, red[3].y));
    smax.z = fmaxf(fmaxf(red[0].z, red[1].z), fmaxf(red[2].z, red[3].z));
    smax.w = fmaxf(fmaxf(red[0].w, red[1].w), fmaxf(red[2].w, red[3].w));
    __syncthreads();

    float4 sm = make_float4(0.f, 0.f, 0.f, 0.f);
    for (int i = start + tid; i < end; i += 256) {
        float4 a = la4[i], bq = lb4[i];
        sm.x += __expf(a.x + bq.x - smax.x); sm.y += __expf(a.y + bq.y - smax.y);
        sm.z += __expf(a.z + bq.z - smax.z); sm.w += __expf(a.w + bq.w - smax.w);
    }
    #pragma unroll
    for (int ofs = 32; ofs >= 1; ofs >>= 1) {
        sm.x += __shfl_xor(sm.x, ofs, 64);
        sm.y += __shfl_xor(sm.y, ofs, 64);
        sm.z += __shfl_xor(sm.z, ofs, 64);
        sm.w += __shfl_xor(sm.w, ofs, 64);
    }
    if (lane == 0) red[wid] = sm;
    __syncthreads();
    if (tid == 0) {
        float4 ssum;
        ssum.x = red[0].x + red[1].x + red[2].x + red[3].x;
        ssum.y = red[0].y + red[1].y + red[2].y + red[3].y;
        ssum.z = red[0].z + red[1].z + red[2].z + red[3].z;
        ssum.w = red[0].w + red[1].w + red[2].w + red[3].w;
        *(float4*)(out + (size_t)b * HD)     = smax;
        *(float4*)(out + (size_t)b * HD + 4) = ssum;
    }
}

// ---------------------------------------------------------------------------
// K3: attn = e/(sum+eps) (written over lgA = final attn out); z = sum attn*x;
//     graph_emb[b,:] = z @ Wt + (sum attn)*bt
// ---------------------------------------------------------------------------
__global__ __launch_bounds__(256) void k3_pool(
    const int* __restrict__ batch, const float* __restrict__ x,
    const float* __restrict__ Wt, const float* __restrict__ bt,
    const float* __restrict__ lgB, float* __restrict__ out, int N)
{
    const int b = blockIdx.x;
    const int tid = threadIdx.x;
    const int start = lower_bound(batch, N, b);
    const int end   = lower_bound(batch, N, b + 1);

    float4* at4 = (float4*)(out + (size_t)NSEG * HD);   // lgA now, attn after
    const float4* lb4 = (const float4*)lgB;

    const float4 smax = *(const float4*)(out + (size_t)b * HD);
    const float4 ssum = *(const float4*)(out + (size_t)b * HD + 4);
    float4 inv;
    inv.x = 1.0f / (ssum.x + 1e-16f); inv.y = 1.0f / (ssum.y + 1e-16f);
    inv.z = 1.0f / (ssum.z + 1e-16f); inv.w = 1.0f / (ssum.w + 1e-16f);

    float z0 = 0.f, z1 = 0.f, z2 = 0.f, z3 = 0.f;
    __shared__ float4 attn_s[256];

    for (int c0 = start; c0 < end; c0 += 256) {
        const int idx = c0 + tid;
        if (idx < end) {
            float4 l = at4[idx];
            float4 lb = lb4[idx];
            float4 a;
            a.x = __expf(l.x + lb.x - smax.x) * inv.x;
            a.y = __expf(l.y + lb.y - smax.y) * inv.y;
            a.z = __expf(l.z + lb.z - smax.z) * inv.z;
            a.w = __expf(l.w + lb.w - smax.w) * inv.w;
            at4[idx] = a;          // final attn output
            attn_s[tid] = a;
        }
        __syncthreads();
        const int cnt = min(256, end - c0);
        const float* xb = x + (size_t)c0 * HD + tid;
        #pragma unroll 4
        for (int i = 0; i < cnt; ++i) {
            float4 a = attn_s[i];
            float xv = xb[(size_t)i * HD];
            z0 = fmaf(a.x, xv, z0); z1 = fmaf(a.y, xv, z1);
            z2 = fmaf(a.z, xv, z2); z3 = fmaf(a.w, xv, z3);
        }
        __syncthreads();
    }

    __shared__ float zs[NHEAD][HD];
    zs[0][tid] = z0; zs[1][tid] = z1; zs[2][tid] = z2; zs[3][tid] = z3;
    __syncthreads();

    const int h = tid >> 6;                      // wave-uniform
    float smh, invh;
    if      (h == 0) { smh = ssum.x; invh = inv.x; }
    else if (h == 1) { smh = ssum.y; invh = inv.y; }
    else if (h == 2) { smh = ssum.z; invh = inv.z; }
    else             { smh = ssum.w; invh = inv.w; }

    float acc = smh * invh * bt[tid];            // (sum attn_h) * bt[j]
    #pragma unroll 4
    for (int k = 0; k < HD; ++k)
        acc = fmaf(zs[h][k], Wt[(size_t)k * HD + tid], acc);

    out[(size_t)b * HD + tid] = acc;             // overwrites stats stash: ok
}

// ---------------------------------------------------------------------------
extern "C" void kernel_launch(void* const* d_in, const int* in_sizes, int n_in,
                              void* d_out, int out_size, void* d_ws, size_t ws_size,
                              hipStream_t stream) {
    const float* x   = (const float*)d_in[0];
    const int*   bat = (const int*)  d_in[1];
    const float* W1  = (const float*)d_in[2];
    const float* b1  = (const float*)d_in[3];
    const float* W2  = (const float*)d_in[4];
    const float* b2  = (const float*)d_in[5];
    const float* Wt  = (const float*)d_in[6];
    const float* bt  = (const float*)d_in[7];
    float* out = (float*)d_out;
    const int N = in_sizes[0] / HD;

    float* lgA = out + (size_t)NSEG * HD;          // attn region of d_out
    char*  wsW = (char*)d_ws;                      // [0,256K): split W planes
    float* lgB = (float*)((char*)d_ws + 262144);   // [256K,+6.4M): partial logits

    hipLaunchKernelGGL(k0_prep, dim3(128), dim3(256), 0, stream, W1, wsW);
    hipLaunchKernelGGL(k1_mfma, dim3(((NRB64 + 7) / 8) * 16), dim3(K1_THREADS),
                       K1_LDS, stream, x, wsW, b1, W2, b2, lgA, lgB, N);
    hipLaunchKernelGGL(k2_seg, dim3(NSEG), dim3(256), 0, stream, bat, lgA, lgB, out, N);
    hipLaunchKernelGGL(k3_pool, dim3(NSEG), dim3(256), 0, stream, bat, x, Wt, bt, lgB, out, N);
}

// Round 13
// 334.111 us; speedup vs baseline: 1.3487x; 1.1160x over previous
//
#include <hip/hip_runtime.h>
#include <math.h>

#define HD    256
#define NHEAD 4
#define NSEG  1024
#define RPB   64                                    // rows per block
#define NRB64 6250                                  // 400000/64 row slabs

typedef short bf16x8 __attribute__((ext_vector_type(8)));
typedef float f32x16 __attribute__((ext_vector_type(16)));

__device__ __forceinline__ float tanh_fast(float v) {
    float e = __expf(2.0f * v);                    // overflow->inf, tanh->1: ok
    return 1.0f - 2.0f * __builtin_amdgcn_rcpf(e + 1.0f);
}

// split fp32 pair into packed bf16-hi word and bf16-lo word (truncation split;
// lo captures mantissa bits 9..17 -> per-product rel err ~2^-17). Used for W.
__device__ __forceinline__ void split2(float a, float b, unsigned &hi, unsigned &lo) {
    unsigned ba = __float_as_uint(a), bb = __float_as_uint(b);
    unsigned ha = ba & 0xFFFF0000u, hb = bb & 0xFFFF0000u;
    float la = a - __uint_as_float(ha);
    float lb = b - __uint_as_float(hb);
    hi = (ha >> 16) | hb;
    lo = (__float_as_uint(la) >> 16) | (__float_as_uint(lb) & 0xFFFF0000u);
}

// round-to-nearest bf16 pack: dst = [bf16(b) : bf16(a)] (a in low 16)
__device__ __forceinline__ unsigned cvt_pk_bf16(float a, float b) {
    unsigned r;
    asm("v_cvt_pk_bf16_f32 %0, %1, %2" : "=v"(r) : "v"(a), "v"(b));
    return r;
}

__device__ __forceinline__ void gld16(const void* g, void* l) {
    __builtin_amdgcn_global_load_lds(
        (const __attribute__((address_space(1))) void*)g,
        (__attribute__((address_space(3))) void*)l, 16, 0, 0);
}

// ---------------------------------------------------------------------------
// k0_prep: W1 (fp32 [k][c]) -> ws split-bf16 planes laid out exactly as k1's
// per-chunk LDS image, KC=16: chunk t (k in [16t,16t+16)):
//   off = t*16384 + ch*8192 + o*2048 + c*16 + j*4   (hi plane; lo at +4096)
// with o = k_local>>3, c = col within 128-col half, j = k-pair. 256 KiB total.
// ---------------------------------------------------------------------------
__global__ __launch_bounds__(256) void k0_prep(
    const float* __restrict__ W1, char* __restrict__ ws)
{
    int g = blockIdx.x * 256 + threadIdx.x;        // 32768 threads
    int c  = g & 127;
    int j  = (g >> 7) & 3;
    int o  = (g >> 9) & 1;
    int ch = (g >> 10) & 1;
    int t  = g >> 11;                              // 0..15
    int k   = t*16 + o*8 + 2*j;
    int col = ch*128 + c;
    float a = W1[(size_t)k * HD + col];
    float b = W1[(size_t)(k + 1) * HD + col];
    unsigned hw, lw;
    split2(a, b, hw, lw);
    size_t off = (size_t)t*16384 + ch*8192 + o*2048 + c*16 + j*4;
    *(unsigned*)(ws + off)        = hw;
    *(unsigned*)(ws + off + 4096) = lw;
}

// ---------------------------------------------------------------------------
// K1: partial logits for one 128-col half.
// 256 thr = 4 waves: rg=wid>>1 (2 x 32 rows), cg=wid&1 (2 x 64 cols);
// wave tile 32x64 = 2 x 32x32 mfma, acc = 32 AGPR.
// NUMERICS (2-term): logits ~= xh@W1h + xh@W1l, xh = rn-bf16(x) via
// v_cvt_pk_bf16_f32 (4 instrs/frag vs 48 for 3-term split2); W1 stays
// hi+lo (2^-17). New error = (x-xh)@W1 ~ 1e-3 on logits; threshold 7e-3.
// SYNC STRUCTURE (replay-proven R5/R6/R8/R11/R12): per chunk, STAGE(t+1)
// first (loads fly under compute), compute chunk t, __syncthreads().
// KC=16: buffer [W 8K][x 4K] x2 = 24K staging; epilogue 32K (p_lds overlays
// h-hi plane after reads) -> LDS 32K -> 5 blocks/CU, 20 waves/CU.
// x image: row-major [64 rows][64B=4 slots], source-side slot^=(row&3).
// Epilogue: tanh -> h split-bf16 planes -> h@W2 via 24 MFMA -> D scatter.
// ---------------------------------------------------------------------------
#define K1_THREADS 256
#define BUFB 12288
#define K1_LDS 32768

__global__ __launch_bounds__(K1_THREADS, 5) void k1_mfma(
    const float* __restrict__ x, const char* __restrict__ wsW,
    const float* __restrict__ b1, const float* __restrict__ W2,
    const float* __restrict__ b2, float* __restrict__ lgA,
    float* __restrict__ lgB, int N)
{
    extern __shared__ __align__(16) char smem[];

    const int raw = blockIdx.x;
    const int ch  = (raw >> 3) & 1;
    const int rb  = (raw >> 4) * 8 + (raw & 7);
    if (rb >= NRB64) return;

    const int tid  = threadIdx.x;
    const int lane = tid & 63;
    const int lo5  = lane & 31;
    const int hi   = lane >> 5;
    const int wid  = tid >> 6;
    const int rg   = wid >> 1;                     // 0..1 (32-row groups)
    const int cg   = wid & 1;                      // 0..1 (64-col groups)
    const int blkrow = rb * RPB;
    const int rl   = rg*32 + lo5;                  // local row this lane computes

    f32x16 acc[2];
    #pragma unroll
    for (int ct = 0; ct < 2; ++ct) {
        float b1v = b1[ch*128 + cg*64 + ct*32 + lo5];
        #pragma unroll
        for (int e = 0; e < 16; ++e) acc[ct][e] = b1v;
    }

    // stage sources. W: linear from pre-split ws (2 x 16B per thread).
    // x: row-major [row][slot] image, slot pre-swizzled (slot ^ row&3).
    const char* gwbase = wsW + ch*8192 + tid*16;   // + u*16384 per chunk
    const char* gxbase;
    {
        int row  = tid >> 2;                       // 0..63
        int slot = tid & 3;
        long grow = blkrow + row; if (grow > N-1) grow = N-1;
        gxbase = (const char*)x + grow*1024 + ((slot ^ (row & 3)) * 16);
    }

    auto STAGE = [&](int u) {                      // u uniform (unrolled const)
        const int db = (u & 1) * BUFB;
        const char* w = gwbase + (size_t)u*16384;
        #pragma unroll
        for (int i = 0; i < 2; ++i)
            gld16(w + i*4096, smem + db + i*4096 + tid*16);
        gld16(gxbase + (size_t)u*64, smem + db + 8192 + tid*16);
    };

    STAGE(0);
    __syncthreads();                               // chunk 0 landed

    #pragma unroll
    for (int t = 0; t < 16; ++t) {
        if (t < 15) STAGE(t + 1);                  // fly under compute
        const int buf = (t & 1) * BUFB;
        {
            union { unsigned u[4]; bf16x8 v; } ah;
            {   // A: x fp32 rows from LDS, read-side slot XOR, rn-bf16 pack
                const int s0 = hi*2;
                const int xb = buf + 8192 + rl*64;
                float4 q0 = *(const float4*)(smem + xb + ((s0     ^ (rl & 3)) << 4));
                float4 q1 = *(const float4*)(smem + xb + (((s0+1) ^ (rl & 3)) << 4));
                ah.u[0] = cvt_pk_bf16(q0.x, q0.y);
                ah.u[1] = cvt_pk_bf16(q0.z, q0.w);
                ah.u[2] = cvt_pk_bf16(q1.x, q1.y);
                ah.u[3] = cvt_pk_bf16(q1.z, q1.w);
            }
            bf16x8 bh[2], bl[2];
            #pragma unroll
            for (int ct = 0; ct < 2; ++ct) {
                int off = buf + hi*2048 + (cg*64 + ct*32 + lo5)*16;
                bh[ct] = *(const bf16x8*)(smem + off);
                bl[ct] = *(const bf16x8*)(smem + off + 4096);
            }
            #pragma unroll
            for (int ct = 0; ct < 2; ++ct) {
                acc[ct] = __builtin_amdgcn_mfma_f32_32x32x16_bf16(ah.v, bh[ct], acc[ct], 0, 0, 0);
                acc[ct] = __builtin_amdgcn_mfma_f32_32x32x16_bf16(ah.v, bl[ct], acc[ct], 0, 0, 0);
            }
        }
        __syncthreads();                           // drain stage(t+1) + reuse guard
    }

    // ---- epilogue: tanh -> h planes (split bf16, swizzled [row][col]) ------
    // hi plane [0,16K), lo plane [16K,32K). p_lds overlays [0,1K) AFTER the
    // h-plane reads complete (extra barrier) -> LDS stays 32K (5 blocks/CU).
    #pragma unroll
    for (int ct = 0; ct < 2; ++ct) {
        const int col = cg*64 + ct*32 + lo5;
        #pragma unroll
        for (int e = 0; e < 16; ++e) {
            float h = tanh_fast(acc[ct][e]);
            int row = rg*32 + (e & 3) + 8*(e >> 2) + 4*hi;
            unsigned hh = __float_as_uint(h) & 0xFFFF0000u;
            float hl = h - __uint_as_float(hh);
            int byte = row*256 + ((((col >> 3) ^ (row & 15))) << 4) + (col & 7)*2;
            *(unsigned short*)(smem + byte)         = (unsigned short)(hh >> 16);
            *(unsigned short*)(smem + 16384 + byte) = (unsigned short)(__float_as_uint(hl) >> 16);
        }
    }
    __syncthreads();

    f32x16 d;
    #pragma unroll
    for (int e = 0; e < 16; ++e) d[e] = 0.0f;
    const int rt_e  = wid;                         // waves 0,1 active
    const int row_e = rt_e*32 + lo5;
    const int colh  = lo5 & 3;
    const bool act  = (wid < 2) && (lo5 < 4);
    if (wid < 2) {
        #pragma unroll
        for (int kk = 0; kk < 8; ++kk) {
            int sb = row_e*256 + (((kk*2 + hi) ^ (row_e & 15)) << 4);
            bf16x8 ahh = *(const bf16x8*)(smem + sb);
            bf16x8 alo = *(const bf16x8*)(smem + 16384 + sb);
            union { unsigned short s[8]; bf16x8 v; } wh, wl;
            #pragma unroll
            for (int j = 0; j < 8; ++j) {
                float w = W2[(size_t)(ch*128 + kk*16 + hi*8 + j)*NHEAD + colh];
                w = act ? w : 0.0f;
                unsigned hb = __float_as_uint(w) & 0xFFFF0000u;
                float wlf = w - __uint_as_float(hb);
                wh.s[j] = (unsigned short)(hb >> 16);
                wl.s[j] = (unsigned short)(__float_as_uint(wlf) >> 16);
            }
            d = __builtin_amdgcn_mfma_f32_32x32x16_bf16(ahh, wh.v, d, 0, 0, 0);
            d = __builtin_amdgcn_mfma_f32_32x32x16_bf16(ahh, wl.v, d, 0, 0, 0);
            d = __builtin_amdgcn_mfma_f32_32x32x16_bf16(alo, wh.v, d, 0, 0, 0);
        }
    }
    __syncthreads();                               // all h-plane reads done

    float* p_lds = (float*)smem;                   // [64][4] overlays h-hi
    if (act) {                                     // D scatter by C-layout
        #pragma unroll
        for (int e = 0; e < 16; ++e) {
            int r = rt_e*32 + (e & 3) + 8*(e >> 2) + 4*hi;
            p_lds[r*4 + lo5] = d[e];
        }
    }
    __syncthreads();
    if (tid < RPB) {
        int grow = blkrow + tid;
        if (grow < N) {
            float4 o = *(float4*)(p_lds + tid*4);
            float* dst;
            if (ch == 0) {
                o.x += b2[0]; o.y += b2[1]; o.z += b2[2]; o.w += b2[3];
                dst = lgA;
            } else dst = lgB;
            *(float4*)(dst + (size_t)grow * NHEAD) = o;
        }
    }
}

// ---------------------------------------------------------------------------
__device__ __forceinline__ int lower_bound(const int* __restrict__ a, int n, int v) {
    int lo = 0, hi = n;
    while (lo < hi) { int m = (lo + hi) >> 1; if (a[m] < v) lo = m + 1; else hi = m; }
    return lo;
}

// ---------------------------------------------------------------------------
// K2: per-segment max & sum-of-exp of (lgA+lgB); stats -> out[b*256+0..7]
// ---------------------------------------------------------------------------
__global__ __launch_bounds__(256) void k2_seg(
    const int* __restrict__ batch, const float* __restrict__ lgA,
    const float* __restrict__ lgB, float* __restrict__ out, int N)
{
    const int b = blockIdx.x;
    const int tid = threadIdx.x;
    const int lane = tid & 63, wid = tid >> 6;
    const int start = lower_bound(batch, N, b);
    const int end   = lower_bound(batch, N, b + 1);
    const float4* la4 = (const float4*)lgA;
    const float4* lb4 = (const float4*)lgB;

    float4 mx = make_float4(-INFINITY, -INFINITY, -INFINITY, -INFINITY);
    for (int i = start + tid; i < end; i += 256) {
        float4 a = la4[i], bq = lb4[i];
        mx.x = fmaxf(mx.x, a.x + bq.x); mx.y = fmaxf(mx.y, a.y + bq.y);
        mx.z = fmaxf(mx.z, a.z + bq.z); mx.w = fmaxf(mx.w, a.w + bq.w);
    }
    #pragma unroll
    for (int ofs = 32; ofs >= 1; ofs >>= 1) {
        mx.x = fmaxf(mx.x, __shfl_xor(mx.x, ofs, 64));
        mx.y = fmaxf(mx.y, __shfl_xor(mx.y, ofs, 64));
        mx.z = fmaxf(mx.z, __shfl_xor(mx.z, ofs, 64));
        mx.w = fmaxf(mx.w, __shfl_xor(mx.w, ofs, 64));
    }
    __shared__ float4 red[4];
    if (lane == 0) red[wid] = mx;
    __syncthreads();
    float4 smax;
    smax.x = fmaxf(fmaxf(red[0].x, red[1].x), fmaxf(red[2].x, red[3].x));
    smax.y = fmaxf(fmaxf(red[0].y, red[1].y), fmaxf(red[2].y, red[3].y));
    smax.z = fmaxf(fmaxf(red[0].z, red[1].z), fmaxf(red[2].z, red[3].z));
    smax.w = fmaxf(fmaxf(red[0].w, red[1].w), fmaxf(red[2].w, red[3].w));
    __syncthreads();

    float4 sm = make_float4(0.f, 0.f, 0.f, 0.f);
    for (int i = start + tid; i < end; i += 256) {
        float4 a = la4[i], bq = lb4[i];
        sm.x += __expf(a.x + bq.x - smax.x); sm.y += __expf(a.y + bq.y - smax.y);
        sm.z += __expf(a.z + bq.z - smax.z); sm.w += __expf(a.w + bq.w - smax.w);
    }
    #pragma unroll
    for (int ofs = 32; ofs >= 1; ofs >>= 1) {
        sm.x += __shfl_xor(sm.x, ofs, 64);
        sm.y += __shfl_xor(sm.y, ofs, 64);
        sm.z += __shfl_xor(sm.z, ofs, 64);
        sm.w += __shfl_xor(sm.w, ofs, 64);
    }
    if (lane == 0) red[wid] = sm;
    __syncthreads();
    if (tid == 0) {
        float4 ssum;
        ssum.x = red[0].x + red[1].x + red[2].x + red[3].x;
        ssum.y = red[0].y + red[1].y + red[2].y + red[3].y;
        ssum.z = red[0].z + red[1].z + red[2].z + red[3].z;
        ssum.w = red[0].w + red[1].w + red[2].w + red[3].w;
        *(float4*)(out + (size_t)b * HD)     = smax;
        *(float4*)(out + (size_t)b * HD + 4) = ssum;
    }
}

// ---------------------------------------------------------------------------
// K3: attn = e/(sum+eps) (written over lgA = final attn out); z = sum attn*x;
//     graph_emb[b,:] = z @ Wt + (sum attn)*bt
// ---------------------------------------------------------------------------
__global__ __launch_bounds__(256) void k3_pool(
    const int* __restrict__ batch, const float* __restrict__ x,
    const float* __restrict__ Wt, const float* __restrict__ bt,
    const float* __restrict__ lgB, float* __restrict__ out, int N)
{
    const int b = blockIdx.x;
    const int tid = threadIdx.x;
    const int start = lower_bound(batch, N, b);
    const int end   = lower_bound(batch, N, b + 1);

    float4* at4 = (float4*)(out + (size_t)NSEG * HD);   // lgA now, attn after
    const float4* lb4 = (const float4*)lgB;

    const float4 smax = *(const float4*)(out + (size_t)b * HD);
    const float4 ssum = *(const float4*)(out + (size_t)b * HD + 4);
    float4 inv;
    inv.x = 1.0f / (ssum.x + 1e-16f); inv.y = 1.0f / (ssum.y + 1e-16f);
    inv.z = 1.0f / (ssum.z + 1e-16f); inv.w = 1.0f / (ssum.w + 1e-16f);

    float z0 = 0.f, z1 = 0.f, z2 = 0.f, z3 = 0.f;
    __shared__ float4 attn_s[256];

    for (int c0 = start; c0 < end; c0 += 256) {
        const int idx = c0 + tid;
        if (idx < end) {
            float4 l = at4[idx];
            float4 lb = lb4[idx];
            float4 a;
            a.x = __expf(l.x + lb.x - smax.x) * inv.x;
            a.y = __expf(l.y + lb.y - smax.y) * inv.y;
            a.z = __expf(l.z + lb.z - smax.z) * inv.z;
            a.w = __expf(l.w + lb.w - smax.w) * inv.w;
            at4[idx] = a;          // final attn output
            attn_s[tid] = a;
        }
        __syncthreads();
        const int cnt = min(256, end - c0);
        const float* xb = x + (size_t)c0 * HD + tid;
        #pragma unroll 4
        for (int i = 0; i < cnt; ++i) {
            float4 a = attn_s[i];
            float xv = xb[(size_t)i * HD];
            z0 = fmaf(a.x, xv, z0); z1 = fmaf(a.y, xv, z1);
            z2 = fmaf(a.z, xv, z2); z3 = fmaf(a.w, xv, z3);
        }
        __syncthreads();
    }

    __shared__ float zs[NHEAD][HD];
    zs[0][tid] = z0; zs[1][tid] = z1; zs[2][tid] = z2; zs[3][tid] = z3;
    __syncthreads();

    const int h = tid >> 6;                      // wave-uniform
    float smh, invh;
    if      (h == 0) { smh = ssum.x; invh = inv.x; }
    else if (h == 1) { smh = ssum.y; invh = inv.y; }
    else if (h == 2) { smh = ssum.z; invh = inv.z; }
    else             { smh = ssum.w; invh = inv.w; }

    float acc = smh * invh * bt[tid];            // (sum attn_h) * bt[j]
    #pragma unroll 4
    for (int k = 0; k < HD; ++k)
        acc = fmaf(zs[h][k], Wt[(size_t)k * HD + tid], acc);

    out[(size_t)b * HD + tid] = acc;             // overwrites stats stash: ok
}

// ---------------------------------------------------------------------------
extern "C" void kernel_launch(void* const* d_in, const int* in_sizes, int n_in,
                              void* d_out, int out_size, void* d_ws, size_t ws_size,
                              hipStream_t stream) {
    const float* x   = (const float*)d_in[0];
    const int*   bat = (const int*)  d_in[1];
    const float* W1  = (const float*)d_in[2];
    const float* b1  = (const float*)d_in[3];
    const float* W2  = (const float*)d_in[4];
    const float* b2  = (const float*)d_in[5];
    const float* Wt  = (const float*)d_in[6];
    const float* bt  = (const float*)d_in[7];
    float* out = (float*)d_out;
    const int N = in_sizes[0] / HD;

    float* lgA = out + (size_t)NSEG * HD;          // attn region of d_out
    char*  wsW = (char*)d_ws;                      // [0,256K): split W planes
    float* lgB = (float*)((char*)d_ws + 262144);   // [256K,+6.4M): partial logits

    hipLaunchKernelGGL(k0_prep, dim3(128), dim3(256), 0, stream, W1, wsW);
    hipLaunchKernelGGL(k1_mfma, dim3(((NRB64 + 7) / 8) * 16), dim3(K1_THREADS),
                       K1_LDS, stream, x, wsW, b1, W2, b2, lgA, lgB, N);
    hipLaunchKernelGGL(k2_seg, dim3(NSEG), dim3(256), 0, stream, bat, lgA, lgB, out, N);
    hipLaunchKernelGGL(k3_pool, dim3(NSEG), dim3(256), 0, stream, bat, x, Wt, bt, lgB, out, N);
}